// Round 3
// baseline (120.563 us; speedup 1.0000x reference)
//
#include <hip/hip_runtime.h>

#define NT 256
#define DM 64
#define NH 4

// ---------------------------------------------------------------------------
// Kernel 1: fused QV projection. grid 256 x 256 thr, 4 tokens/block.
// Thread r computes output rows r (q, pre-scaled by wk) and r+256 (vf).
// vb (rows 512..767 of wqv_w) is dead in the reference -> skipped.
// ---------------------------------------------------------------------------
__global__ __launch_bounds__(256) void k_proj(const float* __restrict__ x,
                                              const float* __restrict__ wk,
                                              const float* __restrict__ wqv_w,
                                              const float* __restrict__ wqv_b,
                                              float* __restrict__ q_s,
                                              float* __restrict__ vf)
{
    __shared__ float xs[4 * DM];
    const int tid  = threadIdx.x;
    const int tok0 = blockIdx.x * 4;

    if (tid < 64)
        reinterpret_cast<float4*>(xs)[tid] =
            reinterpret_cast<const float4*>(x + tok0 * DM)[tid];
    __syncthreads();

    const float4* wr0 = reinterpret_cast<const float4*>(wqv_w + tid * DM);
    const float4* wr1 = reinterpret_cast<const float4*>(wqv_w + (tid + 256) * DM);
    float a0[4] = {0.f, 0.f, 0.f, 0.f};
    float a1[4] = {0.f, 0.f, 0.f, 0.f};

#pragma unroll
    for (int c4 = 0; c4 < 16; ++c4) {
        const float4 wa = wr0[c4];
        const float4 wb = wr1[c4];
#pragma unroll
        for (int t = 0; t < 4; ++t) {
            const float4 xv = reinterpret_cast<const float4*>(xs + t * DM)[c4];
            a0[t] += xv.x * wa.x + xv.y * wa.y + xv.z * wa.z + xv.w * wa.w;
            a1[t] += xv.x * wb.x + xv.y * wb.y + xv.z * wb.z + xv.w * wb.w;
        }
    }

    const int h = tid >> 6, w = tid & 63;
    const float ba = wqv_b[tid];
    const float bb = wqv_b[tid + 256];
    const float kw = wk[h * DM + w];
#pragma unroll
    for (int t = 0; t < 4; ++t) {
        const int g = tok0 + t, b = g >> 8, tt = g & 255;
        const int o = ((b * NH + h) * NT + tt) * DM + w;
        q_s[o] = (a0[t] + ba) * kw;
        vf[o]  =  a1[t] + bb;
    }
}

// ---------------------------------------------------------------------------
// Kernel 2: L1-distance attention. grid (16 qtile, 16 bh) x 1024 thr.
// 16 waves/block (4/SIMD): wave w owns query qt*16+w, q row in registers.
// Distance: lane = key within 64-key chunk, float2 LDS reads (pad 66:
// conflict-free per quarter-wave), double-buffered ks -> 1 sync/chunk.
// Softmax: full-wave shfl_xor reduce (4 key-slots per lane).
// PV: thread = (wq16, q16, sr4): 1q x 4w x 64s, 4 FMA per b128, partial
// sums reduced through LDS.
// ---------------------------------------------------------------------------
#define KS_LD 66
#define AF_LD 258

__global__ __launch_bounds__(1024) void k_attn(const float* __restrict__ x,
                                               const float* __restrict__ wk,
                                               const float* __restrict__ q_s,
                                               const float* __restrict__ vf,
                                               float* __restrict__ bf)
{
    __shared__ float ks[2][64 * KS_LD];    // 33.8 KB double-buffered key tile
    __shared__ float af[16 * AF_LD];       // 16.1 KB softmax weights
    __shared__ float vfs[NT * DM];         // 64 KB v tile (linear, conflict-free)
    __shared__ float part[4 * 16 * DM];    // 16 KB PV partials

    const int tid  = threadIdx.x;
    const int qt   = blockIdx.x;
    const int bh   = blockIdx.y;
    const int b    = bh >> 2, h = bh & 3;
    const int wv   = tid >> 6;             // wave index = query index
    const int lane = tid & 63;

    // ---- stage vfs (issue global loads early; ds_writes drain at syncs) ----
    {
        const float4* vp = reinterpret_cast<const float4*>(vf + (size_t)(b * NH + h) * NT * DM);
        float4* vs = reinterpret_cast<float4*>(vfs);
#pragma unroll
        for (int it = 0; it < 4; ++it)
            vs[it * 1024 + tid] = vp[it * 1024 + tid];
    }

    // ---- q row into registers (all 64 lanes load same row: broadcast) ----
    float q[DM];
    {
        const float4* qp = reinterpret_cast<const float4*>(
            q_s + (size_t)((b * NH + h) * NT + qt * 16 + wv) * DM);
#pragma unroll
        for (int i = 0; i < 16; ++i) {
            const float4 u = qp[i];
            q[4*i+0] = u.x; q[4*i+1] = u.y; q[4*i+2] = u.z; q[4*i+3] = u.w;
        }
    }

    // ---- staging setup: one float4 per thread per chunk ----
    const int srow = tid >> 4;             // 0..63
    const int sc0  = (tid & 15) * 4;       // 0..60
    const float4 wv4 = reinterpret_cast<const float4*>(wk + h * DM)[sc0 >> 2];
    const float* xbase = x + (size_t)b * NT * DM;

    auto STAGE = [&](int cc) {
        const float4 xv = *reinterpret_cast<const float4*>(
            xbase + (cc * 64 + srow) * DM + sc0);
        float* kp = &ks[cc & 1][srow * KS_LD + sc0];
        reinterpret_cast<float2*>(kp)[0] = make_float2(xv.x * wv4.x, xv.y * wv4.y);
        reinterpret_cast<float2*>(kp)[1] = make_float2(xv.z * wv4.z, xv.w * wv4.w);
    };

    // ---- distance: 4 chunks of 64 keys, 1 key/lane/chunk ----
    float dacc[4];
    STAGE(0);
    __syncthreads();
#pragma unroll
    for (int cc = 0; cc < 4; ++cc) {
        if (cc < 3) STAGE(cc + 1);
        const float2* kp = reinterpret_cast<const float2*>(&ks[cc & 1][lane * KS_LD]);
        float d = 0.f;
#pragma unroll
        for (int c2 = 0; c2 < 32; ++c2) {
            const float2 kv = kp[c2];
            d += fabsf(q[2*c2] - kv.x) + fabsf(q[2*c2+1] - kv.y);
        }
        dacc[cc] = d;
        __syncthreads();
    }

    // ---- huber + softmax over 256 keys (4 slots/lane, wave64 reduce) ----
    const float delta = 0.2f;
    float aa[4], m = -1e30f;
#pragma unroll
    for (int j = 0; j < 4; ++j) {
        const float d  = dacc[j] * 0.125f;
        const float hb = (d < delta) ? 0.5f * d * d : delta * (d - 0.5f * delta);
        aa[j] = -hb;
        m = fmaxf(m, aa[j]);
    }
#pragma unroll
    for (int mask = 1; mask < 64; mask <<= 1)
        m = fmaxf(m, __shfl_xor(m, mask, 64));
    float s = 0.f;
#pragma unroll
    for (int j = 0; j < 4; ++j) { aa[j] = __expf(aa[j] - m); s += aa[j]; }
#pragma unroll
    for (int mask = 1; mask < 64; mask <<= 1)
        s += __shfl_xor(s, mask, 64);
    const float rs = 1.f / s;
#pragma unroll
    for (int j = 0; j < 4; ++j)
        af[wv * AF_LD + j * 64 + lane] = aa[j] * rs;
    __syncthreads();                       // af + vfs ready

    // ---- PV: thread = (wq 0..15, q 0..15, sr 0..3) ----
    {
        const int wq = tid & 15;
        const int qq = (tid >> 4) & 15;
        const int sr = tid >> 8;
        float4 acc = make_float4(0.f, 0.f, 0.f, 0.f);
        const float* afr = af + qq * AF_LD + sr * 64;
        const float* vb  = vfs + (sr * 64) * DM + wq * 4;
#pragma unroll 8
        for (int s2 = 0; s2 < 64; ++s2) {
            const float a  = afr[s2];
            const float4 v = *reinterpret_cast<const float4*>(vb + s2 * DM);
            acc.x += a * v.x; acc.y += a * v.y; acc.z += a * v.z; acc.w += a * v.w;
        }
        *reinterpret_cast<float4*>(&part[(sr * 16 + qq) * DM + wq * 4]) = acc;
    }
    __syncthreads();

    // ---- reduce partials over sr, write bf (wave = query, lane = w) ----
    {
        const float* pp = part + wv * DM + lane;
        const float r = pp[0] + pp[1024] + pp[2048] + pp[3072];
        bf[(size_t)((b * NH + h) * NT + qt * 16 + wv) * DM + lane] = r;
    }
}

// ---------------------------------------------------------------------------
// Kernel 3: b = sum_h bf; y = silu_1.702(b); out = x + y @ fanin_w.T + bias.
// grid 256 x 256 thr, 4 tokens/block.
// ---------------------------------------------------------------------------
__global__ __launch_bounds__(256) void k_out(const float* __restrict__ x,
                                             const float* __restrict__ bf,
                                             const float* __restrict__ fanin_w,
                                             const float* __restrict__ fanin_b,
                                             float* __restrict__ out)
{
    __shared__ float fw[64 * 68];
    __shared__ float ys[4 * DM];

    const int tid  = threadIdx.x;
    const int tok0 = blockIdx.x * 4;

#pragma unroll
    for (int it = 0; it < 4; ++it) {
        const int qidx = it * 256 + tid;
        const int row = qidx >> 4, cq = qidx & 15;
        *reinterpret_cast<float4*>(fw + row * 68 + cq * 4) =
            reinterpret_cast<const float4*>(fanin_w)[qidx];
    }
    {
        const int t = tid >> 6, c = tid & 63;
        const int g = tok0 + t, b = g >> 8, tt = g & 255;
        float s = 0.f;
#pragma unroll
        for (int hh = 0; hh < NH; ++hh)
            s += bf[((b * NH + hh) * NT + tt) * DM + c];
        ys[t * DM + c] = s / (1.f + __expf(-1.702f * s));
    }
    __syncthreads();
    {
        const int t = tid >> 6, w = tid & 63;
        float acc = fanin_b[w];
        const float* yr = ys + t * DM;
        const float* fr = fw + w * 68;
#pragma unroll
        for (int c4 = 0; c4 < 16; ++c4) {
            const float4 yv = *reinterpret_cast<const float4*>(yr + c4 * 4);
            const float4 fv = *reinterpret_cast<const float4*>(fr + c4 * 4);
            acc += yv.x * fv.x + yv.y * fv.y + yv.z * fv.z + yv.w * fv.w;
        }
        const int g = tok0 + t;
        out[g * DM + w] = x[g * DM + w] + acc;
    }
}

// ---------------------------------------------------------------------------
extern "C" void kernel_launch(void* const* d_in, const int* in_sizes, int n_in,
                              void* d_out, int out_size, void* d_ws, size_t ws_size,
                              hipStream_t stream) {
    const float* x       = (const float*)d_in[0];
    const float* wk      = (const float*)d_in[1];
    const float* wqv_w   = (const float*)d_in[2];
    const float* wqv_b   = (const float*)d_in[3];
    const float* fanin_w = (const float*)d_in[4];
    const float* fanin_b = (const float*)d_in[5];
    float* out = (float*)d_out;

    float* ws  = (float*)d_ws;
    float* q_s = ws;                   // [4][4][256][64]
    float* vfw = ws + 262144;
    float* bfw = ws + 524288;

    hipLaunchKernelGGL(k_proj, dim3(256),    dim3(256),  0, stream,
                       x, wk, wqv_w, wqv_b, q_s, vfw);
    hipLaunchKernelGGL(k_attn, dim3(16, 16), dim3(1024), 0, stream,
                       x, wk, q_s, vfw, bfw);
    hipLaunchKernelGGL(k_out,  dim3(256),    dim3(256),  0, stream,
                       x, bfw, fanin_w, fanin_b, out);
}

// Round 6
// 120.260 us; speedup vs baseline: 1.0025x; 1.0025x over previous
//
#include <hip/hip_runtime.h>

#define NT 256
#define DM 64
#define NH 4

// ---------------------------------------------------------------------------
// Kernel 1: fused QV projection. grid 256 x 256 thr, 4 tokens/block.
// Thread r computes output rows r (q, pre-scaled by wk) and r+256 (vf).
// vb (rows 512..767 of wqv_w) is dead in the reference -> skipped.
// ---------------------------------------------------------------------------
__global__ __launch_bounds__(256) void k_proj(const float* __restrict__ x,
                                              const float* __restrict__ wk,
                                              const float* __restrict__ wqv_w,
                                              const float* __restrict__ wqv_b,
                                              float* __restrict__ q_s,
                                              float* __restrict__ vf)
{
    __shared__ float xs[4 * DM];
    const int tid  = threadIdx.x;
    const int tok0 = blockIdx.x * 4;

    if (tid < 64)
        reinterpret_cast<float4*>(xs)[tid] =
            reinterpret_cast<const float4*>(x + tok0 * DM)[tid];
    __syncthreads();

    const float4* wr0 = reinterpret_cast<const float4*>(wqv_w + tid * DM);
    const float4* wr1 = reinterpret_cast<const float4*>(wqv_w + (tid + 256) * DM);
    float a0[4] = {0.f, 0.f, 0.f, 0.f};
    float a1[4] = {0.f, 0.f, 0.f, 0.f};

#pragma unroll
    for (int c4 = 0; c4 < 16; ++c4) {
        const float4 wa = wr0[c4];
        const float4 wb = wr1[c4];
#pragma unroll
        for (int t = 0; t < 4; ++t) {
            const float4 xv = reinterpret_cast<const float4*>(xs + t * DM)[c4];
            a0[t] += xv.x * wa.x + xv.y * wa.y + xv.z * wa.z + xv.w * wa.w;
            a1[t] += xv.x * wb.x + xv.y * wb.y + xv.z * wb.z + xv.w * wb.w;
        }
    }

    const int h = tid >> 6, w = tid & 63;
    const float ba = wqv_b[tid];
    const float bb = wqv_b[tid + 256];
    const float kw = wk[h * DM + w];
#pragma unroll
    for (int t = 0; t < 4; ++t) {
        const int g = tok0 + t, b = g >> 8, tt = g & 255;
        const int o = ((b * NH + h) * NT + tt) * DM + w;
        q_s[o] = (a0[t] + ba) * kw;
        vf[o]  =  a1[t] + bb;
    }
}

// ---------------------------------------------------------------------------
// Kernel 2: L1-distance attention. grid (16 qtile, 16 bh) x 1024 thr.
// __launch_bounds__(1024, 4): 16 waves/block = 4 waves/EU -> VGPR cap 128.
// (Round-3 lesson: without the 2nd arg the compiler capped at 64 VGPRs and
// spilled q[64] to scratch -> 53 MB scratch fetch, 131 us dispatch.)
// Wave w owns query qt*16+w, q row in 64 VGPRs.
// Distance: lane = key in 64-key chunk, float2 LDS reads (pad 66),
// double-buffered ks -> 1 sync/chunk. Softmax: wave64 shfl_xor reduce.
// PV: thread = (wq16, q16, sr4), partials reduced through LDS.
// ---------------------------------------------------------------------------
#define KS_LD 66
#define AF_LD 258

__global__ __launch_bounds__(1024, 4) void k_attn(const float* __restrict__ x,
                                                  const float* __restrict__ wk,
                                                  const float* __restrict__ q_s,
                                                  const float* __restrict__ vf,
                                                  float* __restrict__ bf)
{
    __shared__ float ks[2][64 * KS_LD];    // 33.8 KB double-buffered key tile
    __shared__ float af[16 * AF_LD];       // 16.1 KB softmax weights
    __shared__ float vfs[NT * DM];         // 64 KB v tile (linear, conflict-free)
    __shared__ float part[4 * 16 * DM];    // 16 KB PV partials

    const int tid  = threadIdx.x;
    const int qt   = blockIdx.x;
    const int bh   = blockIdx.y;
    const int b    = bh >> 2, h = bh & 3;
    const int wv   = tid >> 6;             // wave index = query index
    const int lane = tid & 63;

    // ---- stage vfs (issue global loads early; drains at later syncs) ----
    {
        const float4* vp = reinterpret_cast<const float4*>(vf + (size_t)(b * NH + h) * NT * DM);
        float4* vs = reinterpret_cast<float4*>(vfs);
#pragma unroll
        for (int it = 0; it < 4; ++it)
            vs[it * 1024 + tid] = vp[it * 1024 + tid];
    }

    // ---- q row into registers (all 64 lanes load same row: broadcast) ----
    float q[DM];
    {
        const float4* qp = reinterpret_cast<const float4*>(
            q_s + (size_t)((b * NH + h) * NT + qt * 16 + wv) * DM);
#pragma unroll
        for (int i = 0; i < 16; ++i) {
            const float4 u = qp[i];
            q[4*i+0] = u.x; q[4*i+1] = u.y; q[4*i+2] = u.z; q[4*i+3] = u.w;
        }
    }

    // ---- staging setup: one float4 per thread per chunk ----
    const int srow = tid >> 4;             // 0..63
    const int sc0  = (tid & 15) * 4;       // 0..60
    const float4 wv4 = reinterpret_cast<const float4*>(wk + h * DM)[sc0 >> 2];
    const float* xbase = x + (size_t)b * NT * DM;

    auto STAGE = [&](int cc) {
        const float4 xv = *reinterpret_cast<const float4*>(
            xbase + (cc * 64 + srow) * DM + sc0);
        float* kp = &ks[cc & 1][srow * KS_LD + sc0];
        reinterpret_cast<float2*>(kp)[0] = make_float2(xv.x * wv4.x, xv.y * wv4.y);
        reinterpret_cast<float2*>(kp)[1] = make_float2(xv.z * wv4.z, xv.w * wv4.w);
    };

    // ---- distance: 4 chunks of 64 keys, 1 key/lane/chunk ----
    float dacc[4];
    STAGE(0);
    __syncthreads();
#pragma unroll
    for (int cc = 0; cc < 4; ++cc) {
        if (cc < 3) STAGE(cc + 1);
        const float2* kp = reinterpret_cast<const float2*>(&ks[cc & 1][lane * KS_LD]);
        float d = 0.f;
#pragma unroll
        for (int c2 = 0; c2 < 32; ++c2) {
            const float2 kv = kp[c2];
            d += fabsf(q[2*c2] - kv.x) + fabsf(q[2*c2+1] - kv.y);
        }
        dacc[cc] = d;
        __syncthreads();
    }

    // ---- huber + softmax over 256 keys (4 slots/lane, wave64 reduce) ----
    const float delta = 0.2f;
    float aa[4], m = -1e30f;
#pragma unroll
    for (int j = 0; j < 4; ++j) {
        const float d  = dacc[j] * 0.125f;
        const float hb = (d < delta) ? 0.5f * d * d : delta * (d - 0.5f * delta);
        aa[j] = -hb;
        m = fmaxf(m, aa[j]);
    }
#pragma unroll
    for (int mask = 1; mask < 64; mask <<= 1)
        m = fmaxf(m, __shfl_xor(m, mask, 64));
    float s = 0.f;
#pragma unroll
    for (int j = 0; j < 4; ++j) { aa[j] = __expf(aa[j] - m); s += aa[j]; }
#pragma unroll
    for (int mask = 1; mask < 64; mask <<= 1)
        s += __shfl_xor(s, mask, 64);
    const float rs = 1.f / s;
#pragma unroll
    for (int j = 0; j < 4; ++j)
        af[wv * AF_LD + j * 64 + lane] = aa[j] * rs;
    __syncthreads();                       // af + vfs ready

    // ---- PV: thread = (wq 0..15, q 0..15, sr 0..3) ----
    {
        const int wq = tid & 15;
        const int qq = (tid >> 4) & 15;
        const int sr = tid >> 8;
        float4 acc = make_float4(0.f, 0.f, 0.f, 0.f);
        const float* afr = af + qq * AF_LD + sr * 64;
        const float* vb  = vfs + (sr * 64) * DM + wq * 4;
#pragma unroll 8
        for (int s2 = 0; s2 < 64; ++s2) {
            const float a  = afr[s2];
            const float4 v = *reinterpret_cast<const float4*>(vb + s2 * DM);
            acc.x += a * v.x; acc.y += a * v.y; acc.z += a * v.z; acc.w += a * v.w;
        }
        *reinterpret_cast<float4*>(&part[(sr * 16 + qq) * DM + wq * 4]) = acc;
    }
    __syncthreads();

    // ---- reduce partials over sr, write bf (wave = query, lane = w) ----
    {
        const float* pp = part + wv * DM + lane;
        const float r = pp[0] + pp[1024] + pp[2048] + pp[3072];
        bf[(size_t)((b * NH + h) * NT + qt * 16 + wv) * DM + lane] = r;
    }
}

// ---------------------------------------------------------------------------
// Kernel 3: b = sum_h bf; y = silu_1.702(b); out = x + y @ fanin_w.T + bias.
// grid 256 x 256 thr, 4 tokens/block.
// ---------------------------------------------------------------------------
__global__ __launch_bounds__(256) void k_out(const float* __restrict__ x,
                                             const float* __restrict__ bf,
                                             const float* __restrict__ fanin_w,
                                             const float* __restrict__ fanin_b,
                                             float* __restrict__ out)
{
    __shared__ float fw[64 * 68];
    __shared__ float ys[4 * DM];

    const int tid  = threadIdx.x;
    const int tok0 = blockIdx.x * 4;

#pragma unroll
    for (int it = 0; it < 4; ++it) {
        const int qidx = it * 256 + tid;
        const int row = qidx >> 4, cq = qidx & 15;
        *reinterpret_cast<float4*>(fw + row * 68 + cq * 4) =
            reinterpret_cast<const float4*>(fanin_w)[qidx];
    }
    {
        const int t = tid >> 6, c = tid & 63;
        const int g = tok0 + t, b = g >> 8, tt = g & 255;
        float s = 0.f;
#pragma unroll
        for (int hh = 0; hh < NH; ++hh)
            s += bf[((b * NH + hh) * NT + tt) * DM + c];
        ys[t * DM + c] = s / (1.f + __expf(-1.702f * s));
    }
    __syncthreads();
    {
        const int t = tid >> 6, w = tid & 63;
        float acc = fanin_b[w];
        const float* yr = ys + t * DM;
        const float* fr = fw + w * 68;
#pragma unroll
        for (int c4 = 0; c4 < 16; ++c4) {
            const float4 yv = *reinterpret_cast<const float4*>(yr + c4 * 4);
            const float4 fv = *reinterpret_cast<const float4*>(fr + c4 * 4);
            acc += yv.x * fv.x + yv.y * fv.y + yv.z * fv.z + yv.w * fv.w;
        }
        const int g = tok0 + t;
        out[g * DM + w] = x[g * DM + w] + acc;
    }
}

// ---------------------------------------------------------------------------
extern "C" void kernel_launch(void* const* d_in, const int* in_sizes, int n_in,
                              void* d_out, int out_size, void* d_ws, size_t ws_size,
                              hipStream_t stream) {
    const float* x       = (const float*)d_in[0];
    const float* wk      = (const float*)d_in[1];
    const float* wqv_w   = (const float*)d_in[2];
    const float* wqv_b   = (const float*)d_in[3];
    const float* fanin_w = (const float*)d_in[4];
    const float* fanin_b = (const float*)d_in[5];
    float* out = (float*)d_out;

    float* ws  = (float*)d_ws;
    float* q_s = ws;                   // [4][4][256][64]
    float* vfw = ws + 262144;
    float* bfw = ws + 524288;

    hipLaunchKernelGGL(k_proj, dim3(256),    dim3(256),  0, stream,
                       x, wk, wqv_w, wqv_b, q_s, vfw);
    hipLaunchKernelGGL(k_attn, dim3(16, 16), dim3(1024), 0, stream,
                       x, wk, q_s, vfw, bfw);
    hipLaunchKernelGGL(k_out,  dim3(256),    dim3(256),  0, stream,
                       x, bfw, fanin_w, fanin_b, out);
}

// Round 7
// 117.592 us; speedup vs baseline: 1.0253x; 1.0227x over previous
//
#include <hip/hip_runtime.h>

#define NT 256
#define DM 64
#define NH 4

// ---------------------------------------------------------------------------
// Kernel 1: fused QV projection. grid 256 x 256 thr, 4 tokens/block.
// Thread r computes output rows r (q, pre-scaled by wk) and r+256 (vf).
// vb (rows 512..767 of wqv_w) is dead in the reference -> skipped.
// ---------------------------------------------------------------------------
__global__ __launch_bounds__(256) void k_proj(const float* __restrict__ x,
                                              const float* __restrict__ wk,
                                              const float* __restrict__ wqv_w,
                                              const float* __restrict__ wqv_b,
                                              float* __restrict__ q_s,
                                              float* __restrict__ vf)
{
    __shared__ float xs[4 * DM];
    const int tid  = threadIdx.x;
    const int tok0 = blockIdx.x * 4;

    if (tid < 64)
        reinterpret_cast<float4*>(xs)[tid] =
            reinterpret_cast<const float4*>(x + tok0 * DM)[tid];
    __syncthreads();

    const float4* wr0 = reinterpret_cast<const float4*>(wqv_w + tid * DM);
    const float4* wr1 = reinterpret_cast<const float4*>(wqv_w + (tid + 256) * DM);
    float a0[4] = {0.f, 0.f, 0.f, 0.f};
    float a1[4] = {0.f, 0.f, 0.f, 0.f};

#pragma unroll
    for (int c4 = 0; c4 < 16; ++c4) {
        const float4 wa = wr0[c4];
        const float4 wb = wr1[c4];
#pragma unroll
        for (int t = 0; t < 4; ++t) {
            const float4 xv = reinterpret_cast<const float4*>(xs + t * DM)[c4];
            a0[t] += xv.x * wa.x + xv.y * wa.y + xv.z * wa.z + xv.w * wa.w;
            a1[t] += xv.x * wb.x + xv.y * wb.y + xv.z * wb.z + xv.w * wb.w;
        }
    }

    const int h = tid >> 6, w = tid & 63;
    const float ba = wqv_b[tid];
    const float bb = wqv_b[tid + 256];
    const float kw = wk[h * DM + w];
#pragma unroll
    for (int t = 0; t < 4; ++t) {
        const int g = tok0 + t, b = g >> 8, tt = g & 255;
        const int o = ((b * NH + h) * NT + tt) * DM + w;
        q_s[o] = (a0[t] + ba) * kw;
        vf[o]  =  a1[t] + bb;
    }
}

// ---------------------------------------------------------------------------
// Kernel 2: L1-distance attention. grid (16 qtile, 16 bh) x 1024 thr.
// ROUND-6 LESSON: __launch_bounds__(1024,4) did NOT raise the compiler's
// 64-VGPR occupancy target (it ignored the LDS cap and spilled q[64] ->
// 53/81 MB scratch traffic). Fix: fit in 64 VGPRs by construction.
// Distance phase lane split: kk=lane&15 (key), cs=lane>>4 (16-ch c-slice).
// Thread holds a 16-float q-slice; partial |q-k| sums reduced across cs
// via shfl_xor(16|32). ks b128 reads: bank start (2kk+16(cs&1)+4i)%32 ->
// 2-way conflict = free. Softmax: reduce masks {1,2,4,8} within cs-group.
// PV: thread = (wq16, q16, sr4), partials reduced through LDS.
// ---------------------------------------------------------------------------
#define KS_LD 66
#define AF_LD 258

__global__ __launch_bounds__(1024, 4) void k_attn(const float* __restrict__ x,
                                                  const float* __restrict__ wk,
                                                  const float* __restrict__ q_s,
                                                  const float* __restrict__ vf,
                                                  float* __restrict__ bf)
{
    __shared__ float ks[2][64 * KS_LD];    // 33.8 KB double-buffered key tile
    __shared__ float af[16 * AF_LD];       // 16.1 KB softmax weights
    __shared__ float vfs[NT * DM];         // 64 KB v tile (linear, conflict-free)
    __shared__ float part[4 * 16 * DM];    // 16 KB PV partials

    const int tid  = threadIdx.x;
    const int qt   = blockIdx.x;
    const int bh   = blockIdx.y;
    const int b    = bh >> 2, h = bh & 3;
    const int wv   = tid >> 6;             // wave index = query index
    const int lane = tid & 63;
    const int kk   = lane & 15;            // key-within-16
    const int cs   = lane >> 4;            // c-slice 0..3

    // ---- stage vfs (issue global loads early; drains at later syncs) ----
    {
        const float4* vp = reinterpret_cast<const float4*>(vf + (size_t)(b * NH + h) * NT * DM);
        float4* vs = reinterpret_cast<float4*>(vfs);
#pragma unroll
        for (int it = 0; it < 4; ++it)
            vs[it * 1024 + tid] = vp[it * 1024 + tid];
    }

    // ---- q-slice into registers: 16 floats = q[cs*16 .. cs*16+15] ----
    float4 q0, q1, q2, q3;
    {
        const float4* qp = reinterpret_cast<const float4*>(
            q_s + (size_t)((b * NH + h) * NT + qt * 16 + wv) * DM + cs * 16);
        q0 = qp[0]; q1 = qp[1]; q2 = qp[2]; q3 = qp[3];
    }

    // ---- staging setup: one float4 per thread per chunk ----
    const int srow = tid >> 4;             // 0..63
    const int sc0  = (tid & 15) * 4;       // 0..60
    const float4 wv4 = reinterpret_cast<const float4*>(wk + h * DM)[sc0 >> 2];
    const float* xbase = x + (size_t)b * NT * DM;

    auto STAGE = [&](int cc) {
        const float4 xv = *reinterpret_cast<const float4*>(
            xbase + (cc * 64 + srow) * DM + sc0);
        float* kp = &ks[cc & 1][srow * KS_LD + sc0];
        reinterpret_cast<float2*>(kp)[0] = make_float2(xv.x * wv4.x, xv.y * wv4.y);
        reinterpret_cast<float2*>(kp)[1] = make_float2(xv.z * wv4.z, xv.w * wv4.w);
    };

    // ---- distance: 4 chunks x 4 passes; key = cc*64 + p*16 + kk ----
    float aa[16];
    STAGE(0);
    __syncthreads();
#pragma unroll
    for (int cc = 0; cc < 4; ++cc) {
        if (cc < 3) STAGE(cc + 1);
#pragma unroll
        for (int p = 0; p < 4; ++p) {
            const float4* kp = reinterpret_cast<const float4*>(
                &ks[cc & 1][(p * 16 + kk) * KS_LD + cs * 16]);
            const float4 k0 = kp[0], k1 = kp[1], k2 = kp[2], k3 = kp[3];
            float d = fabsf(q0.x - k0.x) + fabsf(q0.y - k0.y)
                    + fabsf(q0.z - k0.z) + fabsf(q0.w - k0.w)
                    + fabsf(q1.x - k1.x) + fabsf(q1.y - k1.y)
                    + fabsf(q1.z - k1.z) + fabsf(q1.w - k1.w)
                    + fabsf(q2.x - k2.x) + fabsf(q2.y - k2.y)
                    + fabsf(q2.z - k2.z) + fabsf(q2.w - k2.w)
                    + fabsf(q3.x - k3.x) + fabsf(q3.y - k3.y)
                    + fabsf(q3.z - k3.z) + fabsf(q3.w - k3.w);
            // reduce partial sums across the 4 c-slices
            d += __shfl_xor(d, 16, 64);
            d += __shfl_xor(d, 32, 64);
            aa[cc * 4 + p] = d;            // full distance, replicated over cs
        }
        __syncthreads();
    }

    // ---- huber + softmax over 256 keys (16 vals/lane, reduce over kk) ----
    const float delta = 0.2f;
    float m = -1e30f;
#pragma unroll
    for (int j = 0; j < 16; ++j) {
        const float d  = aa[j] * 0.125f;
        const float hb = (d < delta) ? 0.5f * d * d : delta * (d - 0.5f * delta);
        aa[j] = -hb;
        m = fmaxf(m, aa[j]);
    }
#pragma unroll
    for (int mask = 1; mask < 16; mask <<= 1)
        m = fmaxf(m, __shfl_xor(m, mask, 64));
    float s = 0.f;
#pragma unroll
    for (int j = 0; j < 16; ++j) { aa[j] = __expf(aa[j] - m); s += aa[j]; }
#pragma unroll
    for (int mask = 1; mask < 16; mask <<= 1)
        s += __shfl_xor(s, mask, 64);
    const float rs = 1.f / s;
    if (cs == 0) {                         // one replica writes af
#pragma unroll
        for (int j = 0; j < 16; ++j)
            af[wv * AF_LD + (j >> 2) * 64 + (j & 3) * 16 + kk] = aa[j] * rs;
    }
    __syncthreads();                       // af + vfs ready

    // ---- PV: thread = (wq 0..15, q 0..15, sr 0..3) ----
    {
        const int wq = tid & 15;
        const int qq = (tid >> 4) & 15;
        const int sr = tid >> 8;
        float4 acc = make_float4(0.f, 0.f, 0.f, 0.f);
        const float* afr = af + qq * AF_LD + sr * 64;
        const float* vb  = vfs + (sr * 64) * DM + wq * 4;
#pragma unroll 8
        for (int s2 = 0; s2 < 64; ++s2) {
            const float a  = afr[s2];
            const float4 v = *reinterpret_cast<const float4*>(vb + s2 * DM);
            acc.x += a * v.x; acc.y += a * v.y; acc.z += a * v.z; acc.w += a * v.w;
        }
        *reinterpret_cast<float4*>(&part[(sr * 16 + qq) * DM + wq * 4]) = acc;
    }
    __syncthreads();

    // ---- reduce partials over sr, write bf (wave = query, lane = w) ----
    {
        const float* pp = part + wv * DM + lane;
        const float r = pp[0] + pp[1024] + pp[2048] + pp[3072];
        bf[(size_t)((b * NH + h) * NT + qt * 16 + wv) * DM + lane] = r;
    }
}

// ---------------------------------------------------------------------------
// Kernel 3: b = sum_h bf; y = silu_1.702(b); out = x + y @ fanin_w.T + bias.
// grid 256 x 256 thr, 4 tokens/block.
// ---------------------------------------------------------------------------
__global__ __launch_bounds__(256) void k_out(const float* __restrict__ x,
                                             const float* __restrict__ bf,
                                             const float* __restrict__ fanin_w,
                                             const float* __restrict__ fanin_b,
                                             float* __restrict__ out)
{
    __shared__ float fw[64 * 68];
    __shared__ float ys[4 * DM];

    const int tid  = threadIdx.x;
    const int tok0 = blockIdx.x * 4;

#pragma unroll
    for (int it = 0; it < 4; ++it) {
        const int qidx = it * 256 + tid;
        const int row = qidx >> 4, cq = qidx & 15;
        *reinterpret_cast<float4*>(fw + row * 68 + cq * 4) =
            reinterpret_cast<const float4*>(fanin_w)[qidx];
    }
    {
        const int t = tid >> 6, c = tid & 63;
        const int g = tok0 + t, b = g >> 8, tt = g & 255;
        float s = 0.f;
#pragma unroll
        for (int hh = 0; hh < NH; ++hh)
            s += bf[((b * NH + hh) * NT + tt) * DM + c];
        ys[t * DM + c] = s / (1.f + __expf(-1.702f * s));
    }
    __syncthreads();
    {
        const int t = tid >> 6, w = tid & 63;
        float acc = fanin_b[w];
        const float* yr = ys + t * DM;
        const float* fr = fw + w * 68;
#pragma unroll
        for (int c4 = 0; c4 < 16; ++c4) {
            const float4 yv = *reinterpret_cast<const float4*>(yr + c4 * 4);
            const float4 fv = *reinterpret_cast<const float4*>(fr + c4 * 4);
            acc += yv.x * fv.x + yv.y * fv.y + yv.z * fv.z + yv.w * fv.w;
        }
        const int g = tok0 + t;
        out[g * DM + w] = x[g * DM + w] + acc;
    }
}

// ---------------------------------------------------------------------------
extern "C" void kernel_launch(void* const* d_in, const int* in_sizes, int n_in,
                              void* d_out, int out_size, void* d_ws, size_t ws_size,
                              hipStream_t stream) {
    const float* x       = (const float*)d_in[0];
    const float* wk      = (const float*)d_in[1];
    const float* wqv_w   = (const float*)d_in[2];
    const float* wqv_b   = (const float*)d_in[3];
    const float* fanin_w = (const float*)d_in[4];
    const float* fanin_b = (const float*)d_in[5];
    float* out = (float*)d_out;

    float* ws  = (float*)d_ws;
    float* q_s = ws;                   // [4][4][256][64]
    float* vfw = ws + 262144;
    float* bfw = ws + 524288;

    hipLaunchKernelGGL(k_proj, dim3(256),    dim3(256),  0, stream,
                       x, wk, wqv_w, wqv_b, q_s, vfw);
    hipLaunchKernelGGL(k_attn, dim3(16, 16), dim3(1024), 0, stream,
                       x, wk, q_s, vfw, bfw);
    hipLaunchKernelGGL(k_out,  dim3(256),    dim3(256),  0, stream,
                       x, bfw, fanin_w, fanin_b, out);
}

// Round 8
// 96.361 us; speedup vs baseline: 1.2512x; 1.2203x over previous
//
#include <hip/hip_runtime.h>

#define NT 256
#define DM 64
#define NH 4

// ---------------------------------------------------------------------------
// Kernel 1: fused QV projection. grid 256 x 256 thr, 4 tokens/block.
// Thread r computes output rows r (q, pre-scaled by wk) and r+256 (vf).
// vb (rows 512..767 of wqv_w) is dead in the reference -> skipped.
// ---------------------------------------------------------------------------
__global__ __launch_bounds__(256) void k_proj(const float* __restrict__ x,
                                              const float* __restrict__ wk,
                                              const float* __restrict__ wqv_w,
                                              const float* __restrict__ wqv_b,
                                              float* __restrict__ q_s,
                                              float* __restrict__ vf)
{
    __shared__ float xs[4 * DM];
    const int tid  = threadIdx.x;
    const int tok0 = blockIdx.x * 4;

    if (tid < 64)
        reinterpret_cast<float4*>(xs)[tid] =
            reinterpret_cast<const float4*>(x + tok0 * DM)[tid];
    __syncthreads();

    const float4* wr0 = reinterpret_cast<const float4*>(wqv_w + tid * DM);
    const float4* wr1 = reinterpret_cast<const float4*>(wqv_w + (tid + 256) * DM);
    float a0[4] = {0.f, 0.f, 0.f, 0.f};
    float a1[4] = {0.f, 0.f, 0.f, 0.f};

#pragma unroll
    for (int c4 = 0; c4 < 16; ++c4) {
        const float4 wa = wr0[c4];
        const float4 wb = wr1[c4];
#pragma unroll
        for (int t = 0; t < 4; ++t) {
            const float4 xv = reinterpret_cast<const float4*>(xs + t * DM)[c4];
            a0[t] += xv.x * wa.x + xv.y * wa.y + xv.z * wa.z + xv.w * wa.w;
            a1[t] += xv.x * wb.x + xv.y * wb.y + xv.z * wb.z + xv.w * wb.w;
        }
    }

    const int h = tid >> 6, w = tid & 63;
    const float ba = wqv_b[tid];
    const float bb = wqv_b[tid + 256];
    const float kw = wk[h * DM + w];
#pragma unroll
    for (int t = 0; t < 4; ++t) {
        const int g = tok0 + t, b = g >> 8, tt = g & 255;
        const int o = ((b * NH + h) * NT + tt) * DM + w;
        q_s[o] = (a0[t] + ba) * kw;
        vf[o]  =  a1[t] + bb;
    }
}

// ---------------------------------------------------------------------------
// Kernel 2: L1-distance attention. grid (16 qtile, 16 bh) x 1024 thr.
// ROUND-7 LESSON: 12 __syncthreads on a 16-wave block at 1 block/CU ->
// lockstep phases, 80% stall (VALUBusy 17%, dur 40.8 us despite ~8 us of
// real work). Fix: stage EVERYTHING once, ONE barrier, then each wave runs
// its query's full pipeline (distance/softmax/PV/store) independently.
// - ks[256][68]: all 256 key rows of x*wk. Stride 68: float4-aligned,
//   balanced per-bank word counts on both staged writes and b128 reads.
// - vfs[256][64] linear. af: per-wave-private LDS (in-order within wave,
//   no barrier). PV partials reduced via shfl_xor(16|32) - no part[] LDS.
// Distance lane split (64-VGPR-safe, round-6 lesson): kk=lane&15 (key),
// cs=lane>>4 (16-ch slice); q-slice = 16 floats/thread; cross-cs reduce
// via shfl_xor(16|32). Softmax reduce over kk: masks 1,2,4,8.
// ---------------------------------------------------------------------------
#define KS_LD 68
#define AF_B  66   // per-64-key-block stride inside a wave's af row (4 blocks)

__global__ __launch_bounds__(1024, 4) void k_attn(const float* __restrict__ x,
                                                  const float* __restrict__ wk,
                                                  const float* __restrict__ q_s,
                                                  const float* __restrict__ vf,
                                                  float* __restrict__ bf)
{
    __shared__ float ks[256 * KS_LD];      // 69.6 KB: all keys, pre-scaled
    __shared__ float vfs[NT * DM];         // 64 KB
    __shared__ float af[16 * 4 * AF_B];    // 16.9 KB, wave-private rows

    const int tid  = threadIdx.x;
    const int qt   = blockIdx.x;
    const int bh   = blockIdx.y;
    const int b    = bh >> 2, h = bh & 3;
    const int wv   = tid >> 6;             // wave index = query index
    const int lane = tid & 63;
    const int kk   = lane & 15;            // key-within-16 / output w4
    const int cs   = lane >> 4;            // c-slice / s-quarter

    // ---- cooperative staging: ks = x*wk, vfs = vf (one pass, linear q-map) --
    {
        const float4 wkv = reinterpret_cast<const float4*>(wk + h * DM)[tid & 15];
        const float4* xp = reinterpret_cast<const float4*>(x + (size_t)b * NT * DM);
        const float4* vp = reinterpret_cast<const float4*>(vf + (size_t)(b * NH + h) * NT * DM);
        float4* vs = reinterpret_cast<float4*>(vfs);
#pragma unroll
        for (int it = 0; it < 4; ++it) {
            const int qi  = it * 1024 + tid;       // float4 index, 0..4095
            const int row = qi >> 4, c4 = qi & 15; // c4 == tid&15 (1024%16==0)
            const float4 xv = xp[qi];
            *reinterpret_cast<float4*>(&ks[row * KS_LD + c4 * 4]) =
                make_float4(xv.x * wkv.x, xv.y * wkv.y, xv.z * wkv.z, xv.w * wkv.w);
            vs[qi] = vp[qi];
        }
    }

    // ---- q-slice (16 floats = channels cs*16..cs*16+15) into registers ----
    float4 q0, q1, q2, q3;
    {
        const float4* qp = reinterpret_cast<const float4*>(
            q_s + (size_t)((b * NH + h) * NT + qt * 16 + wv) * DM + cs * 16);
        q0 = qp[0]; q1 = qp[1]; q2 = qp[2]; q3 = qp[3];
    }
    __syncthreads();                       // the ONLY barrier in this kernel

    // ---- distance: 16 passes; key = j*16 + kk ----
    float aa[16];
#pragma unroll
    for (int j = 0; j < 16; ++j) {
        const float4* kp = reinterpret_cast<const float4*>(
            &ks[(j * 16 + kk) * KS_LD + cs * 16]);
        const float4 k0 = kp[0], k1 = kp[1], k2 = kp[2], k3 = kp[3];
        float d = fabsf(q0.x - k0.x) + fabsf(q0.y - k0.y)
                + fabsf(q0.z - k0.z) + fabsf(q0.w - k0.w)
                + fabsf(q1.x - k1.x) + fabsf(q1.y - k1.y)
                + fabsf(q1.z - k1.z) + fabsf(q1.w - k1.w)
                + fabsf(q2.x - k2.x) + fabsf(q2.y - k2.y)
                + fabsf(q2.z - k2.z) + fabsf(q2.w - k2.w)
                + fabsf(q3.x - k3.x) + fabsf(q3.y - k3.y)
                + fabsf(q3.z - k3.z) + fabsf(q3.w - k3.w);
        d += __shfl_xor(d, 16, 64);        // reduce partial sums across cs
        d += __shfl_xor(d, 32, 64);
        aa[j] = d;                         // full distance, replicated over cs
    }

    // ---- huber + softmax over 256 keys (16 vals/lane, reduce over kk) ----
    const float delta = 0.2f;
    float m = -1e30f;
#pragma unroll
    for (int j = 0; j < 16; ++j) {
        const float d  = aa[j] * 0.125f;
        const float hb = (d < delta) ? 0.5f * d * d : delta * (d - 0.5f * delta);
        aa[j] = -hb;
        m = fmaxf(m, aa[j]);
    }
#pragma unroll
    for (int mask = 1; mask < 16; mask <<= 1)
        m = fmaxf(m, __shfl_xor(m, mask, 64));
    float s = 0.f;
#pragma unroll
    for (int j = 0; j < 16; ++j) { aa[j] = __expf(aa[j] - m); s += aa[j]; }
#pragma unroll
    for (int mask = 1; mask < 16; mask <<= 1)
        s += __shfl_xor(s, mask, 64);
    const float rs = 1.f / s;
    if (cs == 0) {                         // one replica writes this wave's af
#pragma unroll
        for (int j = 0; j < 16; ++j)       // key s = j*16+kk -> block j>>2
            af[(wv * 4 + (j >> 2)) * AF_B + (j & 3) * 16 + kk] = aa[j] * rs;
    }
    // no barrier: af row is wave-private; LDS ops are in-order per wave

    // ---- PV: lane = (w4 = kk -> channels kk*4..+3, s-quarter = cs) ----
    {
        float4 acc = make_float4(0.f, 0.f, 0.f, 0.f);
        const float* afr = af + (wv * 4 + cs) * AF_B;
        const float* vb  = vfs + (cs * 64) * DM + kk * 4;
#pragma unroll 8
        for (int s2 = 0; s2 < 64; ++s2) {
            const float a  = afr[s2];
            const float4 v = *reinterpret_cast<const float4*>(vb + s2 * DM);
            acc.x += a * v.x; acc.y += a * v.y; acc.z += a * v.z; acc.w += a * v.w;
        }
#pragma unroll
        for (int mask = 16; mask <= 32; mask <<= 1) {   // reduce over cs
            acc.x += __shfl_xor(acc.x, mask, 64);
            acc.y += __shfl_xor(acc.y, mask, 64);
            acc.z += __shfl_xor(acc.z, mask, 64);
            acc.w += __shfl_xor(acc.w, mask, 64);
        }
        if (cs == 0) {
            float* op = bf + (size_t)((b * NH + h) * NT + qt * 16 + wv) * DM + kk * 4;
            *reinterpret_cast<float4*>(op) = acc;
        }
    }
}

// ---------------------------------------------------------------------------
// Kernel 3: b = sum_h bf; y = silu_1.702(b); out = x + y @ fanin_w.T + bias.
// grid 256 x 256 thr, 4 tokens/block.
// ---------------------------------------------------------------------------
__global__ __launch_bounds__(256) void k_out(const float* __restrict__ x,
                                             const float* __restrict__ bf,
                                             const float* __restrict__ fanin_w,
                                             const float* __restrict__ fanin_b,
                                             float* __restrict__ out)
{
    __shared__ float fw[64 * 68];
    __shared__ float ys[4 * DM];

    const int tid  = threadIdx.x;
    const int tok0 = blockIdx.x * 4;

#pragma unroll
    for (int it = 0; it < 4; ++it) {
        const int qidx = it * 256 + tid;
        const int row = qidx >> 4, cq = qidx & 15;
        *reinterpret_cast<float4*>(fw + row * 68 + cq * 4) =
            reinterpret_cast<const float4*>(fanin_w)[qidx];
    }
    {
        const int t = tid >> 6, c = tid & 63;
        const int g = tok0 + t, b = g >> 8, tt = g & 255;
        float s = 0.f;
#pragma unroll
        for (int hh = 0; hh < NH; ++hh)
            s += bf[((b * NH + hh) * NT + tt) * DM + c];
        ys[t * DM + c] = s / (1.f + __expf(-1.702f * s));
    }
    __syncthreads();
    {
        const int t = tid >> 6, w = tid & 63;
        float acc = fanin_b[w];
        const float* yr = ys + t * DM;
        const float* fr = fw + w * 68;
#pragma unroll
        for (int c4 = 0; c4 < 16; ++c4) {
            const float4 yv = *reinterpret_cast<const float4*>(yr + c4 * 4);
            const float4 fv = *reinterpret_cast<const float4*>(fr + c4 * 4);
            acc += yv.x * fv.x + yv.y * fv.y + yv.z * fv.z + yv.w * fv.w;
        }
        const int g = tok0 + t;
        out[g * DM + w] = x[g * DM + w] + acc;
    }
}

// ---------------------------------------------------------------------------
extern "C" void kernel_launch(void* const* d_in, const int* in_sizes, int n_in,
                              void* d_out, int out_size, void* d_ws, size_t ws_size,
                              hipStream_t stream) {
    const float* x       = (const float*)d_in[0];
    const float* wk      = (const float*)d_in[1];
    const float* wqv_w   = (const float*)d_in[2];
    const float* wqv_b   = (const float*)d_in[3];
    const float* fanin_w = (const float*)d_in[4];
    const float* fanin_b = (const float*)d_in[5];
    float* out = (float*)d_out;

    float* ws  = (float*)d_ws;
    float* q_s = ws;                   // [4][4][256][64]
    float* vfw = ws + 262144;
    float* bfw = ws + 524288;

    hipLaunchKernelGGL(k_proj, dim3(256),    dim3(256),  0, stream,
                       x, wk, wqv_w, wqv_b, q_s, vfw);
    hipLaunchKernelGGL(k_attn, dim3(16, 16), dim3(1024), 0, stream,
                       x, wk, q_s, vfw, bfw);
    hipLaunchKernelGGL(k_out,  dim3(256),    dim3(256),  0, stream,
                       x, bfw, fanin_w, fanin_b, out);
}

// Round 9
// 93.733 us; speedup vs baseline: 1.2862x; 1.0280x over previous
//
#include <hip/hip_runtime.h>

#define NT 256
#define DM 64
#define NH 4

// ---------------------------------------------------------------------------
// Kernel 1: fused QV projection. grid 256 x 256 thr, 4 tokens/block.
// Thread r computes output rows r (q, pre-scaled by wk) and r+256 (vf).
// vb (rows 512..767 of wqv_w) is dead in the reference -> skipped.
// ---------------------------------------------------------------------------
__global__ __launch_bounds__(256) void k_proj(const float* __restrict__ x,
                                              const float* __restrict__ wk,
                                              const float* __restrict__ wqv_w,
                                              const float* __restrict__ wqv_b,
                                              float* __restrict__ q_s,
                                              float* __restrict__ vf)
{
    __shared__ float xs[4 * DM];
    const int tid  = threadIdx.x;
    const int tok0 = blockIdx.x * 4;

    if (tid < 64)
        reinterpret_cast<float4*>(xs)[tid] =
            reinterpret_cast<const float4*>(x + tok0 * DM)[tid];
    __syncthreads();

    const float4* wr0 = reinterpret_cast<const float4*>(wqv_w + tid * DM);
    const float4* wr1 = reinterpret_cast<const float4*>(wqv_w + (tid + 256) * DM);
    float a0[4] = {0.f, 0.f, 0.f, 0.f};
    float a1[4] = {0.f, 0.f, 0.f, 0.f};

#pragma unroll
    for (int c4 = 0; c4 < 16; ++c4) {
        const float4 wa = wr0[c4];
        const float4 wb = wr1[c4];
#pragma unroll
        for (int t = 0; t < 4; ++t) {
            const float4 xv = reinterpret_cast<const float4*>(xs + t * DM)[c4];
            a0[t] += xv.x * wa.x + xv.y * wa.y + xv.z * wa.z + xv.w * wa.w;
            a1[t] += xv.x * wb.x + xv.y * wb.y + xv.z * wb.z + xv.w * wb.w;
        }
    }

    const int h = tid >> 6, w = tid & 63;
    const float ba = wqv_b[tid];
    const float bb = wqv_b[tid + 256];
    const float kw = wk[h * DM + w];
#pragma unroll
    for (int t = 0; t < 4; ++t) {
        const int g = tok0 + t, b = g >> 8, tt = g & 255;
        const int o = ((b * NH + h) * NT + tt) * DM + w;
        q_s[o] = (a0[t] + ba) * kw;
        vf[o]  =  a1[t] + bb;
    }
}

// ---------------------------------------------------------------------------
// Kernel 2: L1-distance attention. grid (16 qtile, 16 bh) x 512 thr.
// ROUND-8 LESSON: one-barrier free-running design works (k_attn ~8 us,
// LDS-throughput-bound: ~2 MB LDS reads/CU). This round: 8 waves x 2
// queries/wave -> every ks/vfs read feeds 2 accumulators -> LDS traffic
// halves. Registers ~100/thread: amdgpu_waves_per_eu(2,4) lifts the
// backend's 64-VGPR occupancy target (launch_bounds 2nd arg did NOT,
// rounds 3/6); occupancy is LDS-capped at 1 block/CU = 2 waves/SIMD
// anyway, so the register headroom costs nothing.
// Lane split: kk=lane&15 (key / output w4), cs=lane>>4 (c-slice /
// s-quarter); cross-cs reduce via shfl_xor(16|32), softmax over kk via
// shfl_xor(1|2|4|8). af wave-private (no barrier: LDS in-order per wave).
// ---------------------------------------------------------------------------
#define KS_LD 68
#define AF_B  66   // per-64-key-block stride inside a query's af row

__global__ __launch_bounds__(512)
__attribute__((amdgpu_waves_per_eu(2, 4)))
void k_attn(const float* __restrict__ x,
            const float* __restrict__ wk,
            const float* __restrict__ q_s,
            const float* __restrict__ vf,
            float* __restrict__ bf)
{
    __shared__ float ks[256 * KS_LD];      // 69.6 KB: all keys, pre-scaled
    __shared__ float vfs[NT * DM];         // 64 KB
    __shared__ float af[16 * 4 * AF_B];    // 16.9 KB, query-private rows

    const int tid  = threadIdx.x;
    const int qt   = blockIdx.x;
    const int bh   = blockIdx.y;
    const int b    = bh >> 2, h = bh & 3;
    const int wv   = tid >> 6;             // wave 0..7: owns queries 2wv,2wv+1
    const int lane = tid & 63;
    const int kk   = lane & 15;            // key-within-16 / output w4
    const int cs   = lane >> 4;            // c-slice / s-quarter

    // ---- cooperative staging: ks = x*wk, vfs = vf (one pass) ----
    {
        const float4 wkv = reinterpret_cast<const float4*>(wk + h * DM)[tid & 15];
        const float4* xp = reinterpret_cast<const float4*>(x + (size_t)b * NT * DM);
        const float4* vp = reinterpret_cast<const float4*>(vf + (size_t)(b * NH + h) * NT * DM);
        float4* vs = reinterpret_cast<float4*>(vfs);
#pragma unroll
        for (int it = 0; it < 8; ++it) {
            const int qi  = it * 512 + tid;        // float4 index, 0..4095
            const int row = qi >> 4, c4 = qi & 15; // c4 == tid&15 (512%16==0)
            const float4 xv = xp[qi];
            *reinterpret_cast<float4*>(&ks[row * KS_LD + c4 * 4]) =
                make_float4(xv.x * wkv.x, xv.y * wkv.y, xv.z * wkv.z, xv.w * wkv.w);
            vs[qi] = vp[qi];
        }
    }

    // ---- 2 q-slices (16 floats each, channels cs*16..+15) into registers --
    float4 qa0, qa1, qa2, qa3, qb0, qb1, qb2, qb3;
    {
        const float4* qpa = reinterpret_cast<const float4*>(
            q_s + (size_t)((b * NH + h) * NT + qt * 16 + 2 * wv) * DM + cs * 16);
        const float4* qpb = qpa + (DM / 4);    // next query row
        qa0 = qpa[0]; qa1 = qpa[1]; qa2 = qpa[2]; qa3 = qpa[3];
        qb0 = qpb[0]; qb1 = qpb[1]; qb2 = qpb[2]; qb3 = qpb[3];
    }
    __syncthreads();                       // the ONLY barrier in this kernel

    // ---- distance: 16 passes; key = j*16 + kk; 2 queries per key-read ----
    float aa0[16], aa1[16];
#pragma unroll
    for (int j = 0; j < 16; ++j) {
        const float4* kp = reinterpret_cast<const float4*>(
            &ks[(j * 16 + kk) * KS_LD + cs * 16]);
        const float4 k0 = kp[0], k1 = kp[1], k2 = kp[2], k3 = kp[3];
        float d0 = fabsf(qa0.x - k0.x) + fabsf(qa0.y - k0.y)
                 + fabsf(qa0.z - k0.z) + fabsf(qa0.w - k0.w)
                 + fabsf(qa1.x - k1.x) + fabsf(qa1.y - k1.y)
                 + fabsf(qa1.z - k1.z) + fabsf(qa1.w - k1.w)
                 + fabsf(qa2.x - k2.x) + fabsf(qa2.y - k2.y)
                 + fabsf(qa2.z - k2.z) + fabsf(qa2.w - k2.w)
                 + fabsf(qa3.x - k3.x) + fabsf(qa3.y - k3.y)
                 + fabsf(qa3.z - k3.z) + fabsf(qa3.w - k3.w);
        float d1 = fabsf(qb0.x - k0.x) + fabsf(qb0.y - k0.y)
                 + fabsf(qb0.z - k0.z) + fabsf(qb0.w - k0.w)
                 + fabsf(qb1.x - k1.x) + fabsf(qb1.y - k1.y)
                 + fabsf(qb1.z - k1.z) + fabsf(qb1.w - k1.w)
                 + fabsf(qb2.x - k2.x) + fabsf(qb2.y - k2.y)
                 + fabsf(qb2.z - k2.z) + fabsf(qb2.w - k2.w)
                 + fabsf(qb3.x - k3.x) + fabsf(qb3.y - k3.y)
                 + fabsf(qb3.z - k3.z) + fabsf(qb3.w - k3.w);
        d0 += __shfl_xor(d0, 16, 64);      // reduce partials across cs
        d0 += __shfl_xor(d0, 32, 64);
        d1 += __shfl_xor(d1, 16, 64);
        d1 += __shfl_xor(d1, 32, 64);
        aa0[j] = d0;                       // full distances, replicated over cs
        aa1[j] = d1;
    }

    // ---- huber + softmax over 256 keys for both queries (reduce over kk) --
    const float delta = 0.2f;
    float m0 = -1e30f, m1 = -1e30f;
#pragma unroll
    for (int j = 0; j < 16; ++j) {
        float d  = aa0[j] * 0.125f;
        float hb = (d < delta) ? 0.5f * d * d : delta * (d - 0.5f * delta);
        aa0[j] = -hb; m0 = fmaxf(m0, aa0[j]);
        d  = aa1[j] * 0.125f;
        hb = (d < delta) ? 0.5f * d * d : delta * (d - 0.5f * delta);
        aa1[j] = -hb; m1 = fmaxf(m1, aa1[j]);
    }
#pragma unroll
    for (int mask = 1; mask < 16; mask <<= 1) {
        m0 = fmaxf(m0, __shfl_xor(m0, mask, 64));
        m1 = fmaxf(m1, __shfl_xor(m1, mask, 64));
    }
    float s0 = 0.f, s1 = 0.f;
#pragma unroll
    for (int j = 0; j < 16; ++j) {
        aa0[j] = __expf(aa0[j] - m0); s0 += aa0[j];
        aa1[j] = __expf(aa1[j] - m1); s1 += aa1[j];
    }
#pragma unroll
    for (int mask = 1; mask < 16; mask <<= 1) {
        s0 += __shfl_xor(s0, mask, 64);
        s1 += __shfl_xor(s1, mask, 64);
    }
    const float rs0 = 1.f / s0, rs1 = 1.f / s1;
    if (cs == 0) {                         // one replica writes af rows
#pragma unroll
        for (int j = 0; j < 16; ++j) {     // key s = j*16+kk -> block j>>2
            const int off = (j & 3) * 16 + kk;
            af[((2 * wv + 0) * 4 + (j >> 2)) * AF_B + off] = aa0[j] * rs0;
            af[((2 * wv + 1) * 4 + (j >> 2)) * AF_B + off] = aa1[j] * rs1;
        }
    }
    // no barrier: af rows are wave-private; LDS ops in-order per wave

    // ---- PV: lane = (w4 = kk, s-quarter = cs); 1 v-read feeds 2 accs ----
    {
        float4 acc0 = make_float4(0.f, 0.f, 0.f, 0.f);
        float4 acc1 = make_float4(0.f, 0.f, 0.f, 0.f);
        const float* afr0 = af + ((2 * wv + 0) * 4 + cs) * AF_B;
        const float* afr1 = af + ((2 * wv + 1) * 4 + cs) * AF_B;
        const float* vb   = vfs + (cs * 64) * DM + kk * 4;
#pragma unroll 8
        for (int s2 = 0; s2 < 64; ++s2) {
            const float4 v = *reinterpret_cast<const float4*>(vb + s2 * DM);
            const float a0 = afr0[s2];
            const float a1 = afr1[s2];
            acc0.x += a0 * v.x; acc0.y += a0 * v.y; acc0.z += a0 * v.z; acc0.w += a0 * v.w;
            acc1.x += a1 * v.x; acc1.y += a1 * v.y; acc1.z += a1 * v.z; acc1.w += a1 * v.w;
        }
#pragma unroll
        for (int mask = 16; mask <= 32; mask <<= 1) {   // reduce over cs
            acc0.x += __shfl_xor(acc0.x, mask, 64);
            acc0.y += __shfl_xor(acc0.y, mask, 64);
            acc0.z += __shfl_xor(acc0.z, mask, 64);
            acc0.w += __shfl_xor(acc0.w, mask, 64);
            acc1.x += __shfl_xor(acc1.x, mask, 64);
            acc1.y += __shfl_xor(acc1.y, mask, 64);
            acc1.z += __shfl_xor(acc1.z, mask, 64);
            acc1.w += __shfl_xor(acc1.w, mask, 64);
        }
        if (cs == 0) {
            float* op = bf + (size_t)((b * NH + h) * NT + qt * 16 + 2 * wv) * DM + kk * 4;
            *reinterpret_cast<float4*>(op)      = acc0;
            *reinterpret_cast<float4*>(op + DM) = acc1;
        }
    }
}

// ---------------------------------------------------------------------------
// Kernel 3: b = sum_h bf; y = silu_1.702(b); out = x + y @ fanin_w.T + bias.
// grid 256 x 256 thr, 4 tokens/block.
// ---------------------------------------------------------------------------
__global__ __launch_bounds__(256) void k_out(const float* __restrict__ x,
                                             const float* __restrict__ bf,
                                             const float* __restrict__ fanin_w,
                                             const float* __restrict__ fanin_b,
                                             float* __restrict__ out)
{
    __shared__ float fw[64 * 68];
    __shared__ float ys[4 * DM];

    const int tid  = threadIdx.x;
    const int tok0 = blockIdx.x * 4;

#pragma unroll
    for (int it = 0; it < 4; ++it) {
        const int qidx = it * 256 + tid;
        const int row = qidx >> 4, cq = qidx & 15;
        *reinterpret_cast<float4*>(fw + row * 68 + cq * 4) =
            reinterpret_cast<const float4*>(fanin_w)[qidx];
    }
    {
        const int t = tid >> 6, c = tid & 63;
        const int g = tok0 + t, b = g >> 8, tt = g & 255;
        float s = 0.f;
#pragma unroll
        for (int hh = 0; hh < NH; ++hh)
            s += bf[((b * NH + hh) * NT + tt) * DM + c];
        ys[t * DM + c] = s / (1.f + __expf(-1.702f * s));
    }
    __syncthreads();
    {
        const int t = tid >> 6, w = tid & 63;
        float acc = fanin_b[w];
        const float* yr = ys + t * DM;
        const float* fr = fw + w * 68;
#pragma unroll
        for (int c4 = 0; c4 < 16; ++c4) {
            const float4 yv = *reinterpret_cast<const float4*>(yr + c4 * 4);
            const float4 fv = *reinterpret_cast<const float4*>(fr + c4 * 4);
            acc += yv.x * fv.x + yv.y * fv.y + yv.z * fv.z + yv.w * fv.w;
        }
        const int g = tok0 + t;
        out[g * DM + w] = x[g * DM + w] + acc;
    }
}

// ---------------------------------------------------------------------------
extern "C" void kernel_launch(void* const* d_in, const int* in_sizes, int n_in,
                              void* d_out, int out_size, void* d_ws, size_t ws_size,
                              hipStream_t stream) {
    const float* x       = (const float*)d_in[0];
    const float* wk      = (const float*)d_in[1];
    const float* wqv_w   = (const float*)d_in[2];
    const float* wqv_b   = (const float*)d_in[3];
    const float* fanin_w = (const float*)d_in[4];
    const float* fanin_b = (const float*)d_in[5];
    float* out = (float*)d_out;

    float* ws  = (float*)d_ws;
    float* q_s = ws;                   // [4][4][256][64]
    float* vfw = ws + 262144;
    float* bfw = ws + 524288;

    hipLaunchKernelGGL(k_proj, dim3(256),    dim3(256), 0, stream,
                       x, wk, wqv_w, wqv_b, q_s, vfw);
    hipLaunchKernelGGL(k_attn, dim3(16, 16), dim3(512), 0, stream,
                       x, wk, q_s, vfw, bfw);
    hipLaunchKernelGGL(k_out,  dim3(256),    dim3(256), 0, stream,
                       x, bfw, fanin_w, fanin_b, out);
}